// Round 5
// baseline (880.308 us; speedup 1.0000x reference)
//
#include <hip/hip_runtime.h>

// Problem constants (fixed by setup_inputs)
#define BB 8
#define DD 32
#define HH 512
#define WW 512
#define HWSZ (HH*WW)          // 262144 = 2^18
#define NPIX (BB*HWSZ)        // 2097152
#define CC 19
#define EPSF 1e-8f

// Global accumulator layout: per class 65 floats:
// [0..31]=sum(x), [32..63]=sum(x/|x|), [64]=count
#define CSTRIDE 65
#define ACCSZ (CC*CSTRIDE)    // 1235 floats

// ---- k1 tiling ----
// Block owns 2048 contiguous pixels of one image; 8 tiles of 256 px.
// STAGING (contiguous!): wave w loads dim-rows 8w..8w+7; per row ONE
// instruction = 64 lanes x float4 = 1KB contiguous (the m13 6.3TB/s pattern).
// Norm partials (8 dims) computed in registers during staging; 4 wave-partials
// summed via a small LDS phase. Phase 2 = dim-pair-owning PROC2 from LDS.
#define P 256                 // px per tile
#define XST 260               // LDS row stride (words); pad 4 -> conflict-free
#define NT1 256
#define NB1 1024              // 4 blocks/CU x 256 CUs, all resident
#define TPBK 8                // tiles per block

// LDS layout (float offsets):
#define LX_INVN (32*XST)          // 8320  invn[256]
#define LX_LABS (LX_INVN + P)     // 8576  labels[256] (int)
#define LX_SSP  (LX_LABS + P)     // 8832  ssp[4][256] wave partial sq-sums
#define LTOT    (LX_SSP + 4*P)    // 9856 floats = 39424 B -> 4 blocks/CU

__global__ void k0_zero(float* __restrict__ acc)
{
    int i = blockIdx.x * 256 + threadIdx.x;
    if (i < ACCSZ) acc[i] = 0.f;
}

// ---- tiny label histogram (counts) -> acc[c*65+64] ----
#define NCB 1024
__global__ __launch_bounds__(256) void k_count(const int* __restrict__ tgt,
                                               float* __restrict__ acc)
{
    __shared__ float h[32*20];   // 32 copies x 19 classes (stride 20)
    const int t = threadIdx.x;
    for (int i = t; i < 32*20; i += 256) h[i] = 0.f;
    __syncthreads();
    float* my = h + (t & 31) * 20;
    const int T = NCB * 256;                 // 262144 threads
    int tid = blockIdx.x * 256 + t;
    for (int i = tid; i < NPIX/4; i += T) {  // 2 iterations
        int4 lv = ((const int4*)tgt)[i];
        unsafeAtomicAdd(my + lv.x, 1.f);
        unsafeAtomicAdd(my + lv.y, 1.f);
        unsafeAtomicAdd(my + lv.z, 1.f);
        unsafeAtomicAdd(my + lv.w, 1.f);
    }
    __syncthreads();
    if (t < CC) {
        float s = 0.f;
        #pragma unroll
        for (int k = 0; k < 32; k++) s += h[k*20 + t];
        unsafeAtomicAdd(acc + t*CSTRIDE + 64, s);
    }
}

// One pixel, both dims of the pair: mask computed ONCE, reused 4x.
#define PROC2(XL, XH, IV, LL)                              \
    {                                                      \
        const float xl_ = (XL), xh_ = (XH);                \
        const float nl_ = xl_ * (IV), nh_ = xh_ * (IV);    \
        const int   l_  = (LL);                            \
        _Pragma("unroll")                                  \
        for (int c = 0; c < CC; c++) {                     \
            const float m_ = (l_ == c) ? 1.0f : 0.0f;      \
            aS[c].x = fmaf(m_, xl_, aS[c].x);              \
            aS[c].y = fmaf(m_, xh_, aS[c].y);              \
            aN[c].x = fmaf(m_, nl_, aN[c].x);              \
            aN[c].y = fmaf(m_, nh_, aN[c].y);              \
        }                                                  \
    }

__global__ __launch_bounds__(NT1, 4) void k1_accum(
    const float* __restrict__ in, const int* __restrict__ tgt,
    float* __restrict__ acc)
{
    __shared__ __align__(16) float sm[LTOT];
    int* const smi = (int*)sm;
    const int t = threadIdx.x;
    const int w = t >> 6;          // wave: stages dim-rows 8w..8w+7
    const int l = t & 63;          // lane: px quad 4l..4l+3 during staging
    const int dp  = t >> 4;        // phase-2: dim-pair 0..15 (dims 2dp,2dp+1)
    const int sub = t & 15;        // phase-2: px sub-slice

    float2 aS[CC], aN[CC];
    #pragma unroll
    for (int c = 0; c < CC; c++) {
        aS[c] = make_float2(0.f, 0.f);
        aN[c] = make_float2(0.f, 0.f);
    }

    const int blk = blockIdx.x;
    const int b   = blk >> 7;               // image (128 blocks per image)
    const int hwb = (blk & 127) << 11;      // 2048-px span within image

    const float* gxr = in + ((size_t)(b*DD + 8*w))*HWSZ + hwb + 4*l;
    const int*   gla = tgt + ((size_t)blk << 11) + t;

    // prologue: contiguous loads for tile 0 (1KB per instruction)
    float4 X[8];
    #pragma unroll
    for (int d = 0; d < 8; d++) X[d] = *(const float4*)(gxr + (size_t)d*HWSZ);
    int LB = *gla;

    #pragma unroll 1
    for (int i = 0; i < TPBK; i++) {
        // partial squared sums over this wave's 8 dims (registers only)
        float4 ss;
        ss.x = X[0].x*X[0].x; ss.y = X[0].y*X[0].y;
        ss.z = X[0].z*X[0].z; ss.w = X[0].w*X[0].w;
        #pragma unroll
        for (int d = 1; d < 8; d++) {
            ss.x = fmaf(X[d].x, X[d].x, ss.x);
            ss.y = fmaf(X[d].y, X[d].y, ss.y);
            ss.z = fmaf(X[d].z, X[d].z, ss.z);
            ss.w = fmaf(X[d].w, X[d].w, ss.w);
        }

        __syncthreads();   // A: all waves done reading previous tile's LDS

        #pragma unroll
        for (int d = 0; d < 8; d++)
            *(float4*)(sm + (8*w + d)*XST + 4*l) = X[d];
        *(float4*)(sm + LX_SSP + w*P + 4*l) = ss;
        smi[LX_LABS + t] = LB;

        __syncthreads();   // B: tile + partials visible

        if (t < 64) {
            float4 s0 = *(const float4*)(sm + LX_SSP +       4*t);
            float4 s1 = *(const float4*)(sm + LX_SSP + P   + 4*t);
            float4 s2 = *(const float4*)(sm + LX_SSP + 2*P + 4*t);
            float4 s3 = *(const float4*)(sm + LX_SSP + 3*P + 4*t);
            float4 iv;
            iv.x = rsqrtf(fmaxf(s0.x + s1.x + s2.x + s3.x, 1e-30f));
            iv.y = rsqrtf(fmaxf(s0.y + s1.y + s2.y + s3.y, 1e-30f));
            iv.z = rsqrtf(fmaxf(s0.z + s1.z + s2.z + s3.z, 1e-30f));
            iv.w = rsqrtf(fmaxf(s0.w + s1.w + s2.w + s3.w, 1e-30f));
            *(float4*)(sm + LX_INVN + 4*t) = iv;
        }

        __syncthreads();   // C: invn visible

        // issue next tile's contiguous loads; latency hides under phase 2
        if (i + 1 < TPBK) {
            gxr += P; gla += P;
            #pragma unroll
            for (int d = 0; d < 8; d++) X[d] = *(const float4*)(gxr + (size_t)d*HWSZ);
            LB = *gla;
        }

        // --- phase 2: dim-pair accumulation from LDS (conflict-free b128) ---
        const float* xlr = sm + (2*dp)*XST;
        const float* xhr = xlr + XST;
        #pragma unroll 2
        for (int k = 0; k < 4; k++) {
            const int px = 4*sub + 64*k;
            float4 xv = *(const float4*)(xlr + px);
            float4 xw = *(const float4*)(xhr + px);
            float4 nv = *(const float4*)(sm + LX_INVN + px);
            int4   lv = *(const int4*)(smi + LX_LABS + px);
            PROC2(xv.x, xw.x, nv.x, lv.x);
            PROC2(xv.y, xw.y, nv.y, lv.y);
            PROC2(xv.z, xw.z, nv.z, lv.z);
            PROC2(xv.w, xw.w, nv.w, lv.w);
        }
    }

    // ---- fold the 16 sub lanes sharing each dp (in-wave butterflies) ----
    #pragma unroll
    for (int c = 0; c < CC; c++) {
        #pragma unroll
        for (int m = 1; m <= 8; m <<= 1) {
            aS[c].x += __shfl_xor(aS[c].x, m);
            aS[c].y += __shfl_xor(aS[c].y, m);
            aN[c].x += __shfl_xor(aN[c].x, m);
            aN[c].y += __shfl_xor(aN[c].y, m);
        }
    }
    // waves own disjoint dim-pairs -> no cross-wave fold needed
    if (sub == 0) {
        const int d0 = 2*dp;
        #pragma unroll
        for (int c = 0; c < CC; c++) {
            unsafeAtomicAdd(acc + c*CSTRIDE + d0,          aS[c].x);
            unsafeAtomicAdd(acc + c*CSTRIDE + d0 + 1,      aS[c].y);
            unsafeAtomicAdd(acc + c*CSTRIDE + 32 + d0,     aN[c].x);
            unsafeAtomicAdd(acc + c*CSTRIDE + 32 + d0 + 1, aN[c].y);
        }
    }
}

// Final: tiny 19-class epilogue. 1 block x 256 threads, deterministic reduction.
__global__ void k3_final(const float* __restrict__ gacc, float* __restrict__ out)
{
    __shared__ float acc[ACCSZ];
    __shared__ float cn[CC];
    __shared__ float pres[CC];
    __shared__ float red[256];
    const int t = threadIdx.x;

    for (int i = t; i < ACCSZ; i += 256) acc[i] = gacc[i];
    __syncthreads();

    float part = 0.f;

    // per-class: norms, presence, sim term.
    // cosine is scale-invariant in the center, so raw sums replace centers:
    // seg_cos_c = (sums_c . S_c) / |sums_c|,  S_c = sum_{n in c} x_n/|x_n|
    if (t < CC) {
        const float* a = acc + t * CSTRIDE;
        float n2 = 0.f, dotS = 0.f;
        #pragma unroll
        for (int dd = 0; dd < DD; dd++) {
            n2   = fmaf(a[dd], a[dd], n2);
            dotS = fmaf(a[dd], a[32 + dd], dotS);
        }
        float count = a[64];
        float den   = fmaxf(count, 1.f);
        float norm  = sqrtf(n2);
        cn[t]   = norm;
        pres[t] = (count > 0.f) ? 1.f : 0.f;
        float segcos = (norm > 0.f) ? (dotS / norm) : 0.f;
        part += (count > 0.f) ? (1.f - segcos / den) : 0.f;
    }
    __syncthreads();

    // diff loss: 19x19 pair terms on raw sums (denominators cancel in cosine)
    for (int p = t; p < CC * CC; p += 256) {
        int i = p / CC, j = p % CC;
        const float* ai = acc + i * CSTRIDE;
        const float* aj = acc + j * CSTRIDE;
        float dot = 0.f;
        #pragma unroll
        for (int dd = 0; dd < DD; dd++) dot = fmaf(ai[dd], aj[dd], dot);
        float ddn  = fmaxf(cn[i] * cn[j], EPSF);
        float cs   = dot / ddn;
        float term = (i == j) ? (1.f - cs) : fmaxf(cs, 0.f);
        part += pres[i] * term * (1.f / (float)CC);
    }

    red[t] = part;
    __syncthreads();
    #pragma unroll
    for (int s = 128; s > 0; s >>= 1) {
        if (t < s) red[t] += red[t + s];
        __syncthreads();
    }
    if (t == 0) out[0] = red[0];
}

extern "C" void kernel_launch(void* const* d_in, const int* in_sizes, int n_in,
                              void* d_out, int out_size, void* d_ws, size_t ws_size,
                              hipStream_t stream)
{
    const float* in  = (const float*)d_in[0];
    const int*   tgt = (const int*)d_in[1];   // harness delivers integer inputs as int32
    float* out = (float*)d_out;
    float* acc = (float*)d_ws;                // 1235 floats ~ 5 KB

    hipLaunchKernelGGL(k0_zero,  dim3((ACCSZ + 255) / 256), dim3(256), 0, stream, acc);
    hipLaunchKernelGGL(k_count,  dim3(NCB),  dim3(256), 0, stream, tgt, acc);
    hipLaunchKernelGGL(k1_accum, dim3(NB1),  dim3(256), 0, stream, in, tgt, acc);
    hipLaunchKernelGGL(k3_final, dim3(1),    dim3(256), 0, stream, acc, out);
}

// Round 6
// 506.401 us; speedup vs baseline: 1.7384x; 1.7384x over previous
//
#include <hip/hip_runtime.h>

// Problem constants (fixed by setup_inputs)
#define BB 8
#define DD 32
#define HH 512
#define WW 512
#define HWSZ (HH*WW)          // 262144 = 2^18
#define NPIX (BB*HWSZ)        // 2097152
#define CC 19
#define EPSF 1e-8f

// Global accumulator layout: per class 65 floats:
// [0..31]=sum(x), [32..63]=sum(x/|x|), [64]=count
#define CSTRIDE 65
#define ACCSZ (CC*CSTRIDE)    // 1235 floats

// ---- k1 tiling ----
// Block owns 2048 contiguous pixels of one image; 8 tiles of 256 px.
// STAGING (contiguous!): wave w loads dim-rows 8w..8w+7; per row ONE
// instruction = 64 lanes x float4 = 1KB contiguous (the m13 6.3TB/s pattern).
// Norm partials (8 dims) computed in registers during staging; 4 wave-partials
// summed via a small LDS phase. Phase 2 = dim-pair-owning PROC2 from LDS.
//
// __launch_bounds__(256,2): allocator cap 128 VGPR. Measured across rounds:
// (256,4) caps at 64 VGPR -> live set ~120 spills (R3: 580MB, R5: 1.1GB scratch
// writes). (256,2) -> cap 128; at ~120 VGPR the HW still fits 4 waves/SIMD.
#define P 256                 // px per tile
#define XST 260               // LDS row stride (words); pad 4 -> conflict-free
#define NT1 256
#define NB1 1024              // 4 blocks/CU x 256 CUs, all resident
#define TPBK 8                // tiles per block

// LDS layout (float offsets):
#define LX_INVN (32*XST)          // 8320  invn[256]
#define LX_LABS (LX_INVN + P)     // 8576  labels[256] (int)
#define LX_SSP  (LX_LABS + P)     // 8832  ssp[4][256] wave partial sq-sums
#define LTOT    (LX_SSP + 4*P)    // 9856 floats = 39424 B -> 4 blocks/CU

__global__ void k0_zero(float* __restrict__ acc)
{
    int i = blockIdx.x * 256 + threadIdx.x;
    if (i < ACCSZ) acc[i] = 0.f;
}

// ---- tiny label histogram (counts) -> acc[c*65+64] ----
#define NCB 1024
__global__ __launch_bounds__(256) void k_count(const int* __restrict__ tgt,
                                               float* __restrict__ acc)
{
    __shared__ float h[32*20];   // 32 copies x 19 classes (stride 20)
    const int t = threadIdx.x;
    for (int i = t; i < 32*20; i += 256) h[i] = 0.f;
    __syncthreads();
    float* my = h + (t & 31) * 20;
    const int T = NCB * 256;                 // 262144 threads
    int tid = blockIdx.x * 256 + t;
    for (int i = tid; i < NPIX/4; i += T) {  // 2 iterations
        int4 lv = ((const int4*)tgt)[i];
        unsafeAtomicAdd(my + lv.x, 1.f);
        unsafeAtomicAdd(my + lv.y, 1.f);
        unsafeAtomicAdd(my + lv.z, 1.f);
        unsafeAtomicAdd(my + lv.w, 1.f);
    }
    __syncthreads();
    if (t < CC) {
        float s = 0.f;
        #pragma unroll
        for (int k = 0; k < 32; k++) s += h[k*20 + t];
        unsafeAtomicAdd(acc + t*CSTRIDE + 64, s);
    }
}

// One pixel, both dims of the pair: mask computed ONCE, reused 4x.
#define PROC2(XL, XH, IV, LL)                              \
    {                                                      \
        const float xl_ = (XL), xh_ = (XH);                \
        const float nl_ = xl_ * (IV), nh_ = xh_ * (IV);    \
        const int   l_  = (LL);                            \
        _Pragma("unroll")                                  \
        for (int c = 0; c < CC; c++) {                     \
            const float m_ = (l_ == c) ? 1.0f : 0.0f;      \
            aS[c].x = fmaf(m_, xl_, aS[c].x);              \
            aS[c].y = fmaf(m_, xh_, aS[c].y);              \
            aN[c].x = fmaf(m_, nl_, aN[c].x);              \
            aN[c].y = fmaf(m_, nh_, aN[c].y);              \
        }                                                  \
    }

__global__ __launch_bounds__(NT1, 2) void k1_accum(
    const float* __restrict__ in, const int* __restrict__ tgt,
    float* __restrict__ acc)
{
    __shared__ __align__(16) float sm[LTOT];
    int* const smi = (int*)sm;
    const int t = threadIdx.x;
    const int w = t >> 6;          // wave: stages dim-rows 8w..8w+7
    const int l = t & 63;          // lane: px quad 4l..4l+3 during staging
    const int dp  = t >> 4;        // phase-2: dim-pair 0..15 (dims 2dp,2dp+1)
    const int sub = t & 15;        // phase-2: px sub-slice

    float2 aS[CC], aN[CC];
    #pragma unroll
    for (int c = 0; c < CC; c++) {
        aS[c] = make_float2(0.f, 0.f);
        aN[c] = make_float2(0.f, 0.f);
    }

    const int blk = blockIdx.x;
    const int b   = blk >> 7;               // image (128 blocks per image)
    const int hwb = (blk & 127) << 11;      // 2048-px span within image

    const float* gxr = in + ((size_t)(b*DD + 8*w))*HWSZ + hwb + 4*l;
    const int*   gla = tgt + ((size_t)blk << 11) + t;

    // prologue: contiguous loads for tile 0 (1KB per instruction)
    float4 X[8];
    #pragma unroll
    for (int d = 0; d < 8; d++) X[d] = *(const float4*)(gxr + (size_t)d*HWSZ);
    int LB = *gla;

    #pragma unroll 1
    for (int i = 0; i < TPBK; i++) {
        // partial squared sums over this wave's 8 dims (registers only)
        float4 ss;
        ss.x = X[0].x*X[0].x; ss.y = X[0].y*X[0].y;
        ss.z = X[0].z*X[0].z; ss.w = X[0].w*X[0].w;
        #pragma unroll
        for (int d = 1; d < 8; d++) {
            ss.x = fmaf(X[d].x, X[d].x, ss.x);
            ss.y = fmaf(X[d].y, X[d].y, ss.y);
            ss.z = fmaf(X[d].z, X[d].z, ss.z);
            ss.w = fmaf(X[d].w, X[d].w, ss.w);
        }

        __syncthreads();   // A: all waves done reading previous tile's LDS

        #pragma unroll
        for (int d = 0; d < 8; d++)
            *(float4*)(sm + (8*w + d)*XST + 4*l) = X[d];
        *(float4*)(sm + LX_SSP + w*P + 4*l) = ss;
        smi[LX_LABS + t] = LB;

        __syncthreads();   // B: tile + partials visible

        if (t < 64) {
            float4 s0 = *(const float4*)(sm + LX_SSP +       4*t);
            float4 s1 = *(const float4*)(sm + LX_SSP + P   + 4*t);
            float4 s2 = *(const float4*)(sm + LX_SSP + 2*P + 4*t);
            float4 s3 = *(const float4*)(sm + LX_SSP + 3*P + 4*t);
            float4 iv;
            iv.x = rsqrtf(fmaxf(s0.x + s1.x + s2.x + s3.x, 1e-30f));
            iv.y = rsqrtf(fmaxf(s0.y + s1.y + s2.y + s3.y, 1e-30f));
            iv.z = rsqrtf(fmaxf(s0.z + s1.z + s2.z + s3.z, 1e-30f));
            iv.w = rsqrtf(fmaxf(s0.w + s1.w + s2.w + s3.w, 1e-30f));
            *(float4*)(sm + LX_INVN + 4*t) = iv;
        }

        __syncthreads();   // C: invn visible

        // issue next tile's contiguous loads; latency hides under phase 2
        if (i + 1 < TPBK) {
            gxr += P; gla += P;
            #pragma unroll
            for (int d = 0; d < 8; d++) X[d] = *(const float4*)(gxr + (size_t)d*HWSZ);
            LB = *gla;
        }

        // --- phase 2: dim-pair accumulation from LDS (conflict-free b128) ---
        const float* xlr = sm + (2*dp)*XST;
        const float* xhr = xlr + XST;
        #pragma unroll 2
        for (int k = 0; k < 4; k++) {
            const int px = 4*sub + 64*k;
            float4 xv = *(const float4*)(xlr + px);
            float4 xw = *(const float4*)(xhr + px);
            float4 nv = *(const float4*)(sm + LX_INVN + px);
            int4   lv = *(const int4*)(smi + LX_LABS + px);
            PROC2(xv.x, xw.x, nv.x, lv.x);
            PROC2(xv.y, xw.y, nv.y, lv.y);
            PROC2(xv.z, xw.z, nv.z, lv.z);
            PROC2(xv.w, xw.w, nv.w, lv.w);
        }
    }

    // ---- fold the 16 sub lanes sharing each dp (in-wave butterflies) ----
    #pragma unroll
    for (int c = 0; c < CC; c++) {
        #pragma unroll
        for (int m = 1; m <= 8; m <<= 1) {
            aS[c].x += __shfl_xor(aS[c].x, m);
            aS[c].y += __shfl_xor(aS[c].y, m);
            aN[c].x += __shfl_xor(aN[c].x, m);
            aN[c].y += __shfl_xor(aN[c].y, m);
        }
    }
    // waves own disjoint dim-pairs -> no cross-wave fold needed
    if (sub == 0) {
        const int d0 = 2*dp;
        #pragma unroll
        for (int c = 0; c < CC; c++) {
            unsafeAtomicAdd(acc + c*CSTRIDE + d0,          aS[c].x);
            unsafeAtomicAdd(acc + c*CSTRIDE + d0 + 1,      aS[c].y);
            unsafeAtomicAdd(acc + c*CSTRIDE + 32 + d0,     aN[c].x);
            unsafeAtomicAdd(acc + c*CSTRIDE + 32 + d0 + 1, aN[c].y);
        }
    }
}

// Final: tiny 19-class epilogue. 1 block x 256 threads, deterministic reduction.
__global__ void k3_final(const float* __restrict__ gacc, float* __restrict__ out)
{
    __shared__ float acc[ACCSZ];
    __shared__ float cn[CC];
    __shared__ float pres[CC];
    __shared__ float red[256];
    const int t = threadIdx.x;

    for (int i = t; i < ACCSZ; i += 256) acc[i] = gacc[i];
    __syncthreads();

    float part = 0.f;

    // per-class: norms, presence, sim term.
    // cosine is scale-invariant in the center, so raw sums replace centers:
    // seg_cos_c = (sums_c . S_c) / |sums_c|,  S_c = sum_{n in c} x_n/|x_n|
    if (t < CC) {
        const float* a = acc + t * CSTRIDE;
        float n2 = 0.f, dotS = 0.f;
        #pragma unroll
        for (int dd = 0; dd < DD; dd++) {
            n2   = fmaf(a[dd], a[dd], n2);
            dotS = fmaf(a[dd], a[32 + dd], dotS);
        }
        float count = a[64];
        float den   = fmaxf(count, 1.f);
        float norm  = sqrtf(n2);
        cn[t]   = norm;
        pres[t] = (count > 0.f) ? 1.f : 0.f;
        float segcos = (norm > 0.f) ? (dotS / norm) : 0.f;
        part += (count > 0.f) ? (1.f - segcos / den) : 0.f;
    }
    __syncthreads();

    // diff loss: 19x19 pair terms on raw sums (denominators cancel in cosine)
    for (int p = t; p < CC * CC; p += 256) {
        int i = p / CC, j = p % CC;
        const float* ai = acc + i * CSTRIDE;
        const float* aj = acc + j * CSTRIDE;
        float dot = 0.f;
        #pragma unroll
        for (int dd = 0; dd < DD; dd++) dot = fmaf(ai[dd], aj[dd], dot);
        float ddn  = fmaxf(cn[i] * cn[j], EPSF);
        float cs   = dot / ddn;
        float term = (i == j) ? (1.f - cs) : fmaxf(cs, 0.f);
        part += pres[i] * term * (1.f / (float)CC);
    }

    red[t] = part;
    __syncthreads();
    #pragma unroll
    for (int s = 128; s > 0; s >>= 1) {
        if (t < s) red[t] += red[t + s];
        __syncthreads();
    }
    if (t == 0) out[0] = red[0];
}

extern "C" void kernel_launch(void* const* d_in, const int* in_sizes, int n_in,
                              void* d_out, int out_size, void* d_ws, size_t ws_size,
                              hipStream_t stream)
{
    const float* in  = (const float*)d_in[0];
    const int*   tgt = (const int*)d_in[1];   // harness delivers integer inputs as int32
    float* out = (float*)d_out;
    float* acc = (float*)d_ws;                // 1235 floats ~ 5 KB

    hipLaunchKernelGGL(k0_zero,  dim3((ACCSZ + 255) / 256), dim3(256), 0, stream, acc);
    hipLaunchKernelGGL(k_count,  dim3(NCB),  dim3(256), 0, stream, tgt, acc);
    hipLaunchKernelGGL(k1_accum, dim3(NB1),  dim3(256), 0, stream, in, tgt, acc);
    hipLaunchKernelGGL(k3_final, dim3(1),    dim3(256), 0, stream, acc, out);
}